// Round 5
// baseline (132.416 us; speedup 1.0000x reference)
//
#include <hip/hip_runtime.h>

// DecoderLayer: out[k,n,m] = tanh(sum_p w[k,p]*prev[idx[k,p],n,m] + b[k]),
// gated by (#active parents >= 12).  M=2048, K=4096, NN=4096 (64x64), P=16.
//
// Single fused kernel. Block = 512 threads, owns POS_TILE=8 positions.
// LDS: prev[:, pos0:pos0+8] as 32B rows with XOR'd 16B halves (the R3 layout
// that measured ~0 bank conflicts on random-row ds_read_b128 gathers;
// 16B-stride natural layout measured ~48 extra cyc/instr — never again),
// plus the 2KB isact table (random ds_read_u8 = ~2-way aliasing = free).
// 66KB LDS -> 2 blocks/CU = 16 waves/CU; all 512 blocks co-resident.

#define M_ROWS   2048
#define K_NODES  4096
#define NN       4096
#define POS_TILE 8
#define NTHREADS 512
#define PREV_WORDS (M_ROWS * 8)                 // 32B per row
#define LDS_BYTES  (PREV_WORDS * 4 + M_ROWS)    // 65536 + 2048 = 67584
#define OUT_ELEMS  (K_NODES * NN)
#define ACTIVE_THRESHOLD 12

typedef float f32x4 __attribute__((ext_vector_type(4)));

__device__ __forceinline__ float fast_tanh(float x) {
  float ax = __builtin_fabsf(x);
  float e  = __expf(-2.0f * ax);
  float r  = (1.0f - e) * __builtin_amdgcn_rcpf(1.0f + e);
  return __builtin_copysignf(r, x);
}

// lo = logical positions 0-3, hi = 4-7 of row id (undo the staging XOR).
#define GATHER(idv, lo, hi)                                        \
  { int s_ = ((idv) >> 2) & 1; const float* rp_ = &xs[(idv) << 3]; \
    lo = *(const f32x4*)(rp_ + (s_ << 2));                         \
    hi = *(const f32x4*)(rp_ + ((s_ ^ 1) << 2)); }

__global__ __launch_bounds__(NTHREADS, 4) void decoder_kernel(
    const float* __restrict__ prev, const unsigned int* __restrict__ isact,
    const int* __restrict__ pidx, const float* __restrict__ w,
    const float* __restrict__ b, float* __restrict__ out,
    float* __restrict__ outact) {
  extern __shared__ char smem[];
  float* xs = (float*)smem;
  unsigned char* actl = (unsigned char*)(smem + PREV_WORDS * 4);
  __shared__ int mode_sh;
  const int tid = threadIdx.x;

  if (tid == 0) mode_sh = 0;
  __syncthreads();
  // Marshaling detect: any of the first 512 words >1 => isact is packed bytes
  // (e.g. 0x01010100); int32 bools only produce words 0/1.  (0.9-density
  // Bernoulli makes a false word-mode read astronomically unlikely.)
  if (isact[tid] > 1u) atomicOr(&mode_sh, 1);

  // XCD-chunked swizzle: tiles sharing 64B prev/out lines are concurrently
  // resident on one XCD -> L2 merges partial-line writes (proven: 65.6MB).
  const int bid  = blockIdx.x;                              // 0..511
  const int tile = (bid & 7) * (NN / POS_TILE / 8) + (bid >> 3);
  const int pos0 = tile * POS_TILE;

  // ---- stage prev[:, pos0:pos0+8]: row r half h -> word r*8 + ((h^s)*4) ----
  #pragma unroll
  for (int it = 0; it < 8; ++it) {
    int linear = (it << 9) + tid;                           // 0..4095
    int row  = linear >> 1;
    int half = linear & 1;
    int s    = (row >> 2) & 1;
    *(f32x4*)(&xs[(row << 3) + ((half ^ s) << 2)]) =
        *(const f32x4*)(prev + row * NN + pos0 + (half << 2));
  }
  __syncthreads();

  // ---- stage isact as bytes (0/1-ish; compared !=0 at use) ----
  if (mode_sh) {                       // byte mode: raw 2048-byte copy
    ((unsigned int*)actl)[tid] = isact[tid];
  } else {                             // word mode: narrow 0/1 words to bytes
    #pragma unroll
    for (int i = 0; i < 4; ++i) {
      int j = (i << 9) + tid;
      actl[j] = (unsigned char)isact[j];
    }
  }
  __syncthreads();

  for (int kk = 0; kk < K_NODES / NTHREADS; ++kk) {         // 8 iters
    int k = (kk << 9) + tid;
    const int4*   ip = (const int4*)(pidx + (k << 4));
    const float4* wp = (const float4*)(w + (k << 4));
    int4   ia = ip[0], ib = ip[1], ic = ip[2], id4 = ip[3];
    float4 wa = wp[0], wb = wp[1], wc = wp[2], wd = wp[3];
    float  bk = b[k];

    int cnt = (actl[ia.x]  != 0) + (actl[ia.y]  != 0) +
              (actl[ia.z]  != 0) + (actl[ia.w]  != 0) +
              (actl[ib.x]  != 0) + (actl[ib.y]  != 0) +
              (actl[ib.z]  != 0) + (actl[ib.w]  != 0) +
              (actl[ic.x]  != 0) + (actl[ic.y]  != 0) +
              (actl[ic.z]  != 0) + (actl[ic.w]  != 0) +
              (actl[id4.x] != 0) + (actl[id4.y] != 0) +
              (actl[id4.z] != 0) + (actl[id4.w] != 0);
    float g = (cnt >= ACTIVE_THRESHOLD) ? 1.0f : 0.0f;

    f32x4 A0 = {bk, bk, bk, bk}, A1 = {0.f, 0.f, 0.f, 0.f};
    f32x4 B0 = {bk, bk, bk, bk}, B1 = {0.f, 0.f, 0.f, 0.f};
    f32x4 l0,h0,l1,h1,l2,h2,l3,h3,l4,h4,l5,h5,l6,h6,l7,h7;

    // batch 1: parents 0..7 (16 independent ds_read_b128 in flight)
    GATHER(ia.x, l0, h0); GATHER(ia.y, l1, h1);
    GATHER(ia.z, l2, h2); GATHER(ia.w, l3, h3);
    GATHER(ib.x, l4, h4); GATHER(ib.y, l5, h5);
    GATHER(ib.z, l6, h6); GATHER(ib.w, l7, h7);
    A0 += wa.x * l0;  B0 += wa.x * h0;
    A1 += wa.y * l1;  B1 += wa.y * h1;
    A0 += wa.z * l2;  B0 += wa.z * h2;
    A1 += wa.w * l3;  B1 += wa.w * h3;
    A0 += wb.x * l4;  B0 += wb.x * h4;
    A1 += wb.y * l5;  B1 += wb.y * h5;
    A0 += wb.z * l6;  B0 += wb.z * h6;
    A1 += wb.w * l7;  B1 += wb.w * h7;

    // batch 2: parents 8..15
    GATHER(ic.x, l0, h0);  GATHER(ic.y, l1, h1);
    GATHER(ic.z, l2, h2);  GATHER(ic.w, l3, h3);
    GATHER(id4.x, l4, h4); GATHER(id4.y, l5, h5);
    GATHER(id4.z, l6, h6); GATHER(id4.w, l7, h7);
    A0 += wc.x * l0;  B0 += wc.x * h0;
    A1 += wc.y * l1;  B1 += wc.y * h1;
    A0 += wc.z * l2;  B0 += wc.z * h2;
    A1 += wc.w * l3;  B1 += wc.w * h3;
    A0 += wd.x * l4;  B0 += wd.x * h4;
    A1 += wd.y * l5;  B1 += wd.y * h5;
    A0 += wd.z * l6;  B0 += wd.z * h6;
    A1 += wd.w * l7;  B1 += wd.w * h7;

    f32x4 accA = A0 + A1, accB = B0 + B1;
    f32x4 o0, o1;
    o0.x = fast_tanh(accA.x) * g; o0.y = fast_tanh(accA.y) * g;
    o0.z = fast_tanh(accA.z) * g; o0.w = fast_tanh(accA.w) * g;
    o1.x = fast_tanh(accB.x) * g; o1.y = fast_tanh(accB.y) * g;
    o1.z = fast_tanh(accB.z) * g; o1.w = fast_tanh(accB.w) * g;

    float* op = out + (size_t)k * NN + pos0;
    *(f32x4*)op       = o0;
    *(f32x4*)(op + 4) = o1;

    if (pos0 == 0) outact[k] = g;     // block owning tile 0 writes the gate vec
  }
}

extern "C" void kernel_launch(void* const* d_in, const int* in_sizes, int n_in,
                              void* d_out, int out_size, void* d_ws, size_t ws_size,
                              hipStream_t stream) {
  const float* prev  = (const float*)d_in[0];
  const void*  isact = d_in[1];
  const int*   pidx  = (const int*)d_in[2];
  const float* w     = (const float*)d_in[3];
  const float* b     = (const float*)d_in[4];
  float* out    = (float*)d_out;
  float* outact = out + OUT_ELEMS;

  (void)hipFuncSetAttribute((const void*)decoder_kernel,
                            hipFuncAttributeMaxDynamicSharedMemorySize, LDS_BYTES);

  decoder_kernel<<<NN / POS_TILE, NTHREADS, LDS_BYTES, stream>>>(
      prev, (const unsigned int*)isact, pidx, w, b, out, outact);
}

// Round 6
// 93.643 us; speedup vs baseline: 1.4140x; 1.4140x over previous
//
#include <hip/hip_runtime.h>

// DecoderLayer: out[k,n,m] = tanh(sum_p w[k,p]*prev[idx[k,p],n,m] + b[k]),
// gated by (#active parents >= 12).  M=2048, K=4096, NN=4096 (64x64), P=16.
//
// R6 hypothesis test: random-row ds_read_b128 gathers with 64 distinct row
// addresses/wave cost ~50-60 cyc issue occupancy (not bank conflicts).
// Fix: lane-QUAD per node — each wave-gather has only 16 distinct rows,
// contiguous 64B runs. POS_TILE=16 (one full 64B line per row), 128KiB LDS,
// grid = 256 blocks = exactly 1 block/CU; block covers all 4096 nodes.

#define M_ROWS   2048
#define K_NODES  4096
#define NN       4096
#define POS_TILE 16
#define NTHREADS 512
#define LDS_BYTES (M_ROWS * POS_TILE * 4)   // 131072 B (gfx950 allows up to 160K/group)
#define OUT_ELEMS (K_NODES * NN)
#define ACTIVE_THRESHOLD 12

typedef float f32x4 __attribute__((ext_vector_type(4)));

__device__ __forceinline__ float fast_tanh(float x) {
  float ax = __builtin_fabsf(x);
  float e  = __expf(-2.0f * ax);
  float r  = (1.0f - e) * __builtin_amdgcn_rcpf(1.0f + e);
  return __builtin_copysignf(r, x);
}

// Gate precompute (off hot path). Runtime-detects isact marshaling:
// any 32-bit word >1 in the first 2048 bytes implies packed bytes.
__global__ __launch_bounds__(256) void act_kernel(
    const int* __restrict__ pidx, const unsigned int* __restrict__ isact,
    float* __restrict__ outact) {
  __shared__ int mode_sh;
  if (threadIdx.x == 0) mode_sh = 0;
  __syncthreads();
  int bad = 0;
  for (int i = threadIdx.x; i < 512; i += 256) bad |= (isact[i] > 1u);
  if (bad) atomicOr(&mode_sh, 1);
  __syncthreads();
  const int shift = mode_sh ? 0 : 2;   // LSB byte of a 0/1 int32 == its value
  const unsigned char* actb = (const unsigned char*)isact;

  int k = blockIdx.x * 256 + threadIdx.x;
  const int4* ip = (const int4*)(pidx + k * 16);
  int4 ia = ip[0], ib = ip[1], ic = ip[2], id4 = ip[3];
  int ids[16] = {ia.x, ia.y, ia.z, ia.w, ib.x, ib.y, ib.z, ib.w,
                 ic.x, ic.y, ic.z, ic.w, id4.x, id4.y, id4.z, id4.w};
  int n = 0;
  #pragma unroll
  for (int p = 0; p < 16; ++p) n += (actb[ids[p] << shift] != 0);
  outact[k] = (n >= ACTIVE_THRESHOLD) ? 1.0f : 0.0f;
}

// Read logical 16B chunk q of row id (chunks stored at phys = c ^ (id&3)).
#define GQ(idv, dst)                                                   \
  { int ph_ = q ^ ((idv) & 3);                                         \
    dst = *(const f32x4*)(&xs[(((idv) << 4) + (ph_ << 2))]); }

__global__ __launch_bounds__(NTHREADS, 1) void decoder_kernel(
    const float* __restrict__ prev, const int* __restrict__ pidx,
    const float* __restrict__ w, const float* __restrict__ b,
    const float* __restrict__ actf, float* __restrict__ out) {
  extern __shared__ float xs[];   // [2048 rows][16 words], chunk-XOR'd
  const int tid  = threadIdx.x;
  const int pos0 = blockIdx.x * POS_TILE;   // tile = one 64B line per row

  // ---- stage prev[:, pos0:pos0+16]: chunk c of row -> phys c^(row&3) ----
  #pragma unroll
  for (int it = 0; it < 16; ++it) {
    int linear = (it << 9) + tid;           // 0..8191
    int row  = linear >> 2;
    int c    = linear & 3;
    int phys = c ^ (row & 3);
    *(f32x4*)(&xs[(row << 4) + (phys << 2)]) =
        *(const f32x4*)(prev + row * NN + pos0 + (c << 2));
  }
  __syncthreads();

  const int q  = tid & 3;     // logical chunk (4 positions) this lane owns
  const int nq = tid >> 2;    // node-quad index, 0..127

  for (int kk = 0; kk < K_NODES / (NTHREADS / 4); ++kk) {   // 32 iters
    int n = (kk << 7) + nq;
    const int4*   ip = (const int4*)(pidx + (n << 4));
    const float4* wp = (const float4*)(w + (n << 4));
    int4   ia = ip[0], ib = ip[1], ic = ip[2], id4 = ip[3];
    float4 wa = wp[0], wb = wp[1], wc = wp[2], wd = wp[3];
    float  bk = b[n];
    float  g  = actf[n];                    // 0.0 / 1.0

    f32x4 A0 = {bk, bk, bk, bk}, A1 = {0.f, 0.f, 0.f, 0.f};
    f32x4 x0, x1, x2, x3, x4, x5, x6, x7;

    // batch 1: parents 0..7 (each wave-gather: 16 distinct rows, 64B runs)
    GQ(ia.x, x0) GQ(ia.y, x1) GQ(ia.z, x2) GQ(ia.w, x3)
    GQ(ib.x, x4) GQ(ib.y, x5) GQ(ib.z, x6) GQ(ib.w, x7)
    A0 += wa.x * x0;  A1 += wa.y * x1;
    A0 += wa.z * x2;  A1 += wa.w * x3;
    A0 += wb.x * x4;  A1 += wb.y * x5;
    A0 += wb.z * x6;  A1 += wb.w * x7;

    // batch 2: parents 8..15
    GQ(ic.x, x0)  GQ(ic.y, x1)  GQ(ic.z, x2)  GQ(ic.w, x3)
    GQ(id4.x, x4) GQ(id4.y, x5) GQ(id4.z, x6) GQ(id4.w, x7)
    A0 += wc.x * x0;  A1 += wc.y * x1;
    A0 += wc.z * x2;  A1 += wc.w * x3;
    A0 += wd.x * x4;  A1 += wd.y * x5;
    A0 += wd.z * x6;  A1 += wd.w * x7;

    f32x4 acc = A0 + A1;
    f32x4 o;
    o.x = fast_tanh(acc.x) * g;
    o.y = fast_tanh(acc.y) * g;
    o.z = fast_tanh(acc.z) * g;
    o.w = fast_tanh(acc.w) * g;
    // quad writes one contiguous 64B line of out row n
    *(f32x4*)(out + (size_t)n * NN + pos0 + (q << 2)) = o;
  }
}

extern "C" void kernel_launch(void* const* d_in, const int* in_sizes, int n_in,
                              void* d_out, int out_size, void* d_ws, size_t ws_size,
                              hipStream_t stream) {
  const float* prev  = (const float*)d_in[0];
  const void*  isact = d_in[1];
  const int*   pidx  = (const int*)d_in[2];
  const float* w     = (const float*)d_in[3];
  const float* b     = (const float*)d_in[4];
  float* out    = (float*)d_out;
  float* outact = out + OUT_ELEMS;

  (void)hipFuncSetAttribute((const void*)decoder_kernel,
                            hipFuncAttributeMaxDynamicSharedMemorySize, LDS_BYTES);

  act_kernel<<<K_NODES / 256, 256, 0, stream>>>(
      pidx, (const unsigned int*)isact, outact);
  decoder_kernel<<<NN / POS_TILE, NTHREADS, LDS_BYTES, stream>>>(
      prev, pidx, w, b, outact, out);
}